// Round 14
// baseline (96.533 us; speedup 1.0000x reference)
//
#include <hip/hip_runtime.h>
#include <hip/hip_bf16.h>
#include <stdint.h>

#define B_ 512
#define T_ 256
#define D_ 384
#define H_ 64

typedef __attribute__((ext_vector_type(8))) short bf16x8;
typedef __attribute__((ext_vector_type(16))) float f32x16;

__device__ __forceinline__ unsigned short f2bf(float f) {
  union { float f; unsigned int u; } a; a.f = f;
  unsigned int r = (a.u + 0x7FFFu + ((a.u >> 16) & 1u)) >> 16;
  return (unsigned short)r;
}

__device__ __forceinline__ unsigned int pkbf(float lo, float hi) {
  unsigned int r;
  asm("v_cvt_pk_bf16_f32 %0, %1, %2" : "=v"(r) : "v"(lo), "v"(hi));
  return r;
}

// Build wt2 bf16 [24 k16][192 n][16 k]: wt2[k16][n][j] = W_{n/64}[16*k16+j][n%64]
// -> a wave's 32x16 B-fragment (n = nbase+lane&31, k-half = lane>>5) is ONE
//    contiguous 1KB span: fully-coalesced L2-hot global load, no LDS needed.
__global__ void prep_wt(const float* __restrict__ Wq, const float* __restrict__ Wk,
                        const float* __restrict__ Wv, unsigned short* __restrict__ wt) {
  int idx = blockIdx.x * 256 + threadIdx.x;
  if (idx >= 24 * 192 * 16) return;
  int k16 = idx / 3072;
  int rem = idx - k16 * 3072;
  int n = rem >> 4;
  int j = rem & 15;
  int k = 16 * k16 + j;
  int sel = n >> 6, c = n & 63;
  const float* W = (sel == 0) ? Wq : ((sel == 1) ? Wk : Wv);
  wt[idx] = f2bf(W[k * 64 + c]);
}

// One block per batch, 1024 thr = 16 waves (8 rg x 2 cg), LDS 98304 B.
// Phase 1: ZERO barriers, ZERO LDS. Wave owns 32 rows x 96 cols; per k16-step:
// x JIT from global (32B/lane fp32; cg-duplicate hits L2), B-frag = 1KB coalesced
// load from wt2 (L2-resident), 3x mfma_32x32x16 (reg-dim = n, col = x-row).
// Epilogue: Q@0 / K@32768 / Vt@65536, XOR-swizzled (r13 layout); Q/K packed b64.
// ONE __syncthreads, then phase 2 verbatim from the r13 PASS (waves 0-7).
__global__ __launch_bounds__(1024) void attn_fused(
    const float* __restrict__ x, const float* __restrict__ bq,
    const float* __restrict__ bk, const float* __restrict__ bv,
    const unsigned short* __restrict__ wt, float* __restrict__ out) {
  extern __shared__ char smem[];
  const int tid = threadIdx.x;
  const int b = blockIdx.x;
  const int wv = tid >> 6, lane = tid & 63;
  const int lo5 = lane & 31, hi5 = lane >> 5;
  const int rg = wv >> 1, cg = wv & 1;

  const char* xb = (const char*)x + (size_t)b * T_ * D_ * 4;
  const int rowg = 32 * rg + lo5;
  const char* xrow = xb + (size_t)rowg * 1536 + 32 * hi5;        // + 64*w per k16
  const char* wbase = (const char*)wt + 3072 * cg + 32 * lo5 + 16 * hi5;

  f32x16 acc[3];
#pragma unroll
  for (int ci = 0; ci < 3; ++ci) acc[ci] = (f32x16)0.0f;

#pragma unroll 4
  for (int w = 0; w < 24; ++w) {
    float4 f0 = *reinterpret_cast<const float4*>(xrow + 64 * w);
    float4 f1 = *reinterpret_cast<const float4*>(xrow + 64 * w + 16);
    union { bf16x8 v; unsigned int u[4]; } A;
    A.u[0] = pkbf(f0.x, f0.y); A.u[1] = pkbf(f0.z, f0.w);
    A.u[2] = pkbf(f1.x, f1.y); A.u[3] = pkbf(f1.z, f1.w);
    bf16x8 afr = A.v;
#pragma unroll
    for (int ci = 0; ci < 3; ++ci) {
      bf16x8 bw = *reinterpret_cast<const bf16x8*>(wbase + 6144 * w + 1024 * ci);
      acc[ci] = __builtin_amdgcn_mfma_f32_32x32x16_bf16(bw, afr, acc[ci], 0, 0, 0);
    }
  }

  // ---- epilogue: acc[ci] reg r -> n = nbase + (r&3)+8*(r>>2)+4*hi5, row = rowg ----
#pragma unroll
  for (int ci = 0; ci < 3; ++ci) {
    int nbase = 96 * cg + 32 * ci;
    if (nbase < 128) {
      // Q (n<64) or K: row-major [row][128B] swizzled; 4 consecutive n per rb -> b64
      const float* barr = (nbase < 64) ? bq : bk;
      int cb = (nbase < 64) ? nbase : (nbase - 64);
      char* basep = smem + ((nbase < 64) ? 0 : 32768);
#pragma unroll
      for (int rb = 0; rb < 4; ++rb) {
        int c4 = cb + 8 * rb + 4 * hi5;
        float4 b4 = *reinterpret_cast<const float4*>(barr + c4);
        uint2 pv;
        pv.x = pkbf(acc[ci][4 * rb + 0] + b4.x, acc[ci][4 * rb + 1] + b4.y);
        pv.y = pkbf(acc[ci][4 * rb + 2] + b4.z, acc[ci][4 * rb + 3] + b4.w);
        *reinterpret_cast<uint2*>(basep + rowg * 128 + ((2 * c4) ^ ((rowg & 7) << 4))) = pv;
      }
    } else {
      // V: Vt[h][512B] swizzled; h varies per reg -> scalar u16
#pragma unroll
      for (int r = 0; r < 16; ++r) {
        int hh = nbase - 128 + (r & 3) + 8 * (r >> 2) + 4 * hi5;
        unsigned short v = f2bf(acc[ci][r] + bv[hh]);
        *reinterpret_cast<unsigned short*>(
            smem + 65536 + hh * 512 + ((2 * rowg) ^ ((hh & 7) << 4))) = v;
      }
    }
  }
  __syncthreads();

  // ---------------- phase 2 (waves 0-7 only; verbatim r13 PASS) ----------------
  if (wv < 8) {
    const float cexp = 0.09016844005555897f;  // 256^-0.5 * log2(e)

    bf16x8 qf[4];
    {
      int row = 32 * wv + lo5;
#pragma unroll
      for (int s = 0; s < 4; ++s)
        qf[s] = *reinterpret_cast<const bf16x8*>(
            smem + row * 128 + (((32 * s + 16 * hi5)) ^ ((row & 7) << 4)));
    }

    f32x16 o0 = (f32x16)0.0f, o1 = (f32x16)0.0f;
    float lsum = 0.0f;

    for (int kb = 0; kb <= wv; ++kb) {
      f32x16 st = (f32x16)0.0f;
      {
        int row = 32 * kb + lo5;
#pragma unroll
        for (int s = 0; s < 4; ++s) {
          bf16x8 kf = *reinterpret_cast<const bf16x8*>(
              smem + 32768 + row * 128 + (((32 * s + 16 * hi5)) ^ ((row & 7) << 4)));
          st = __builtin_amdgcn_mfma_f32_32x32x16_bf16(kf, qf[s], st, 0, 0, 0);
        }
      }
      float p[16];
#pragma unroll
      for (int r = 0; r < 16; ++r) {
        float e = exp2f(cexp * st[r]);
        if (kb == wv) {
          int keyl = (r & 3) + 8 * (r >> 2) + 4 * hi5;
          if (keyl > lo5) e = 0.0f;   // causal mask
        }
        p[r] = e;
        lsum += e;
      }

      union { bf16x8 v; unsigned int w[4]; } A0, A1;
      {
        unsigned int X0 = pkbf(p[0], p[1]),  X1 = pkbf(p[2], p[3]);
        unsigned int Y0 = pkbf(p[4], p[5]),  Y1 = pkbf(p[6], p[7]);
        unsigned int X0p = (unsigned int)__shfl_xor((int)X0, 32);
        unsigned int X1p = (unsigned int)__shfl_xor((int)X1, 32);
        unsigned int Y0p = (unsigned int)__shfl_xor((int)Y0, 32);
        unsigned int Y1p = (unsigned int)__shfl_xor((int)Y1, 32);
        A0.w[0] = hi5 ? Y0p : X0;
        A0.w[1] = hi5 ? Y1p : X1;
        A0.w[2] = hi5 ? Y0  : X0p;
        A0.w[3] = hi5 ? Y1  : X1p;
        unsigned int Z0 = pkbf(p[8], p[9]),   Z1 = pkbf(p[10], p[11]);
        unsigned int W0 = pkbf(p[12], p[13]), W1 = pkbf(p[14], p[15]);
        unsigned int Z0p = (unsigned int)__shfl_xor((int)Z0, 32);
        unsigned int Z1p = (unsigned int)__shfl_xor((int)Z1, 32);
        unsigned int W0p = (unsigned int)__shfl_xor((int)W0, 32);
        unsigned int W1p = (unsigned int)__shfl_xor((int)W1, 32);
        A1.w[0] = hi5 ? W0p : Z0;
        A1.w[1] = hi5 ? W1p : Z1;
        A1.w[2] = hi5 ? W0  : Z0p;
        A1.w[3] = hi5 ? W1  : Z1p;
      }
#pragma unroll
      for (int s2 = 0; s2 < 2; ++s2) {
        bf16x8 pa = s2 ? A1.v : A0.v;
        int kk = 32 * kb + 16 * s2 + 8 * hi5;
#pragma unroll
        for (int ht = 0; ht < 2; ++ht) {
          int h = 32 * ht + lo5;
          bf16x8 vf = *reinterpret_cast<const bf16x8*>(
              smem + 65536 + h * 512 + (((2 * kk)) ^ ((h & 7) << 4)));
          if (ht == 0) o0 = __builtin_amdgcn_mfma_f32_32x32x16_bf16(pa, vf, o0, 0, 0, 0);
          else         o1 = __builtin_amdgcn_mfma_f32_32x32x16_bf16(pa, vf, o1, 0, 0, 0);
        }
      }
    }

    lsum += __shfl_xor(lsum, 32);
    float inv = 1.0f / lsum;
    float* ob = out + (size_t)b * T_ * H_;
#pragma unroll
    for (int r = 0; r < 16; ++r) {
      int ridx = (r & 3) + 8 * (r >> 2) + 4 * hi5;
      float invr = __shfl(inv, ridx);
      int row = 32 * wv + ridx;
      ob[row * H_ + lo5]      = o0[r] * invr;
      ob[row * H_ + 32 + lo5] = o1[r] * invr;
    }
  }
}

extern "C" void kernel_launch(void* const* d_in, const int* in_sizes, int n_in,
                              void* d_out, int out_size, void* d_ws, size_t ws_size,
                              hipStream_t stream) {
  const float* x  = (const float*)d_in[0];
  const float* Wq = (const float*)d_in[1];
  const float* bq = (const float*)d_in[2];
  const float* Wk = (const float*)d_in[3];
  const float* bk = (const float*)d_in[4];
  const float* Wv = (const float*)d_in[5];
  const float* bv = (const float*)d_in[6];
  unsigned short* wt = (unsigned short*)d_ws;   // wt2: 24*192*16 bf16 = 147456 B
  float* out = (float*)d_out;

  prep_wt<<<288, 256, 0, stream>>>(Wq, Wk, Wv, wt);
  attn_fused<<<B_, 1024, 98304, stream>>>(x, bq, bk, bv, wt, out);
}

// Round 15
// 82.638 us; speedup vs baseline: 1.1681x; 1.1681x over previous
//
#include <hip/hip_runtime.h>
#include <hip/hip_bf16.h>
#include <stdint.h>

#define B_ 512
#define T_ 256
#define D_ 384
#define H_ 64

// LDS map (106496 B, 1 block/CU):
//  WT @ 0     : Wt quarter [192 n][96 k] bf16, row stride 208 B (39936 B)
//  Q  @ 0     : (aliases WT after phase 1) [256][128B] swz      (32768 B)
//  KK @ 40960 : K bf16 [256][128B] swz                          (32768 B)
//  VT @ 73728 : Vt bf16 [64][512B] swz                          (32768 B)
#define KK_ 40960
#define VT_ 73728

typedef __attribute__((ext_vector_type(8))) short bf16x8;
typedef __attribute__((ext_vector_type(16))) float f32x16;

__device__ __forceinline__ unsigned short f2bf(float f) {
  union { float f; unsigned int u; } a; a.f = f;
  unsigned int r = (a.u + 0x7FFFu + ((a.u >> 16) & 1u)) >> 16;
  return (unsigned short)r;
}

__device__ __forceinline__ unsigned int pkbf(float lo, float hi) {
  unsigned int r;
  asm("v_cvt_pk_bf16_f32 %0, %1, %2" : "=v"(r) : "v"(lo), "v"(hi));
  return r;
}

// Build Wt bf16 [192][384]: Wt[n][k] = W_{n/64}[k][n%64]
__global__ void prep_wt(const float* __restrict__ Wq, const float* __restrict__ Wk,
                        const float* __restrict__ Wv, unsigned short* __restrict__ wt) {
  int idx = blockIdx.x * 256 + threadIdx.x;
  if (idx >= 192 * 384) return;
  int n = idx / 384, k = idx - n * 384;
  int sel = n >> 6, c = n & 63;
  const float* W = (sel == 0) ? Wq : ((sel == 1) ? Wk : Wv);
  wt[idx] = f2bf(W[k * 64 + c]);
}

// One block per batch, 1024 thr = 16 waves (8 rg x 2 cg).
// Phase 1: per Wt-quarter {stage [192][96] stride 208 via VGPR; 6 k16-steps:
//   x JIT (32 rows x 32B/lane, rolling depth-2), 3 ds_read_b128 B-frags,
//   3 x mfma_32x32x16 (A=Wt rows=n, B=x cols=row)} -> HALF the ds_reads and
//   HALF the MFMA instructions of the r13 PASS at identical FLOPs.
// Epilogue + phase 2: r14/r13 verified code at new K/Vt offsets.
__global__ __launch_bounds__(1024) void attn_fused(
    const float* __restrict__ x, const float* __restrict__ bq,
    const float* __restrict__ bk, const float* __restrict__ bv,
    const unsigned short* __restrict__ wt, float* __restrict__ out) {
  extern __shared__ char smem[];
  const int tid = threadIdx.x;
  const int b = blockIdx.x;
  const int wv = tid >> 6, lane = tid & 63;
  const int lo5 = lane & 31, hi5 = lane >> 5;
  const int rg = wv >> 1, cg = wv & 1;

  const char* xb = (const char*)x + (size_t)b * T_ * D_ * 4;
  const int rowg = 32 * rg + lo5;                      // x row this lane covers (B-frag col)
  const char* xrow = xb + (size_t)rowg * 1536 + 32 * hi5;

  f32x16 acc[3];
#pragma unroll
  for (int ci = 0; ci < 3; ++ci) acc[ci] = (f32x16)0.0f;

  // rolling depth-2 x buffers; k-step g (0..23): bytes 64g + 32*hi5, 32B/lane
  float4 xA[2], xB[2];
  xA[0] = *reinterpret_cast<const float4*>(xrow);
  xA[1] = *reinterpret_cast<const float4*>(xrow + 16);

  for (int qtr = 0; qtr < 4; ++qtr) {
    if (qtr > 0) __syncthreads();                      // prior quarter reads done
    // stage Wt quarter: 2304 uint4 units (VGPR staging, exec-guard safe)
#pragma unroll
    for (int i = 0; i < 3; ++i) {
      int u = tid + 1024 * i;                          // u < 3072, valid < 2304
      if (u < 2304) {
        int n = u / 12;
        int m = u - 12 * n;
        uint4 v = *reinterpret_cast<const uint4*>(wt + n * 384 + 96 * qtr + 8 * m);
        *reinterpret_cast<uint4*>(smem + n * 208 + 16 * m) = v;
      }
    }
    __syncthreads();
#pragma unroll
    for (int s = 0; s < 6; ++s) {
      int g = 6 * qtr + s;
      float4* cur = ((g & 1) == 0) ? xA : xB;
      float4* nxt = ((g & 1) == 0) ? xB : xA;
      if (g < 23) {
        nxt[0] = *reinterpret_cast<const float4*>(xrow + 64 * (g + 1));
        nxt[1] = *reinterpret_cast<const float4*>(xrow + 64 * (g + 1) + 16);
      }
      union { bf16x8 v; unsigned int u[4]; } A;
      A.u[0] = pkbf(cur[0].x, cur[0].y); A.u[1] = pkbf(cur[0].z, cur[0].w);
      A.u[2] = pkbf(cur[1].x, cur[1].y); A.u[3] = pkbf(cur[1].z, cur[1].w);
      bf16x8 afr = A.v;
#pragma unroll
      for (int ci = 0; ci < 3; ++ci) {
        int n = 96 * cg + 32 * ci + lo5;
        bf16x8 bw = *reinterpret_cast<const bf16x8*>(smem + n * 208 + 32 * s + 16 * hi5);
        acc[ci] = __builtin_amdgcn_mfma_f32_32x32x16_bf16(bw, afr, acc[ci], 0, 0, 0);
      }
    }
  }
  __syncthreads();                                     // WT reads done; epilogue may alias

  // ---- epilogue (r14-verified mapping): reg r -> n = nbase+(r&3)+8*(r>>2)+4*hi5,
  //      col (x-row) = rowg ----
#pragma unroll
  for (int ci = 0; ci < 3; ++ci) {
    int nbase = 96 * cg + 32 * ci;
    if (nbase < 128) {
      const float* barr = (nbase < 64) ? bq : bk;
      int cb = (nbase < 64) ? nbase : (nbase - 64);
      char* basep = smem + ((nbase < 64) ? 0 : KK_);
#pragma unroll
      for (int rb = 0; rb < 4; ++rb) {
        int c4 = cb + 8 * rb + 4 * hi5;
        float4 b4 = *reinterpret_cast<const float4*>(barr + c4);
        uint2 pv;
        pv.x = pkbf(acc[ci][4 * rb + 0] + b4.x, acc[ci][4 * rb + 1] + b4.y);
        pv.y = pkbf(acc[ci][4 * rb + 2] + b4.z, acc[ci][4 * rb + 3] + b4.w);
        *reinterpret_cast<uint2*>(basep + rowg * 128 + ((2 * c4) ^ ((rowg & 7) << 4))) = pv;
      }
    } else {
#pragma unroll
      for (int r = 0; r < 16; ++r) {
        int hh = nbase - 128 + (r & 3) + 8 * (r >> 2) + 4 * hi5;
        unsigned short v = f2bf(acc[ci][r] + bv[hh]);
        *reinterpret_cast<unsigned short*>(
            smem + VT_ + hh * 512 + ((2 * rowg) ^ ((hh & 7) << 4))) = v;
      }
    }
  }
  __syncthreads();

  // ---------------- phase 2 (waves 0-7 only; verbatim r13 PASS) ----------------
  if (wv < 8) {
    const float cexp = 0.09016844005555897f;  // 256^-0.5 * log2(e)

    bf16x8 qf[4];
    {
      int row = 32 * wv + lo5;
#pragma unroll
      for (int s = 0; s < 4; ++s)
        qf[s] = *reinterpret_cast<const bf16x8*>(
            smem + row * 128 + (((32 * s + 16 * hi5)) ^ ((row & 7) << 4)));
    }

    f32x16 o0 = (f32x16)0.0f, o1 = (f32x16)0.0f;
    float lsum = 0.0f;

    for (int kb = 0; kb <= wv; ++kb) {
      f32x16 st = (f32x16)0.0f;
      {
        int row = 32 * kb + lo5;
#pragma unroll
        for (int s = 0; s < 4; ++s) {
          bf16x8 kf = *reinterpret_cast<const bf16x8*>(
              smem + KK_ + row * 128 + (((32 * s + 16 * hi5)) ^ ((row & 7) << 4)));
          st = __builtin_amdgcn_mfma_f32_32x32x16_bf16(kf, qf[s], st, 0, 0, 0);
        }
      }
      float p[16];
#pragma unroll
      for (int r = 0; r < 16; ++r) {
        float e = exp2f(cexp * st[r]);
        if (kb == wv) {
          int keyl = (r & 3) + 8 * (r >> 2) + 4 * hi5;
          if (keyl > lo5) e = 0.0f;   // causal mask
        }
        p[r] = e;
        lsum += e;
      }

      union { bf16x8 v; unsigned int w[4]; } A0, A1;
      {
        unsigned int X0 = pkbf(p[0], p[1]),  X1 = pkbf(p[2], p[3]);
        unsigned int Y0 = pkbf(p[4], p[5]),  Y1 = pkbf(p[6], p[7]);
        unsigned int X0p = (unsigned int)__shfl_xor((int)X0, 32);
        unsigned int X1p = (unsigned int)__shfl_xor((int)X1, 32);
        unsigned int Y0p = (unsigned int)__shfl_xor((int)Y0, 32);
        unsigned int Y1p = (unsigned int)__shfl_xor((int)Y1, 32);
        A0.w[0] = hi5 ? Y0p : X0;
        A0.w[1] = hi5 ? Y1p : X1;
        A0.w[2] = hi5 ? Y0  : X0p;
        A0.w[3] = hi5 ? Y1  : X1p;
        unsigned int Z0 = pkbf(p[8], p[9]),   Z1 = pkbf(p[10], p[11]);
        unsigned int W0 = pkbf(p[12], p[13]), W1 = pkbf(p[14], p[15]);
        unsigned int Z0p = (unsigned int)__shfl_xor((int)Z0, 32);
        unsigned int Z1p = (unsigned int)__shfl_xor((int)Z1, 32);
        unsigned int W0p = (unsigned int)__shfl_xor((int)W0, 32);
        unsigned int W1p = (unsigned int)__shfl_xor((int)W1, 32);
        A1.w[0] = hi5 ? W0p : Z0;
        A1.w[1] = hi5 ? W1p : Z1;
        A1.w[2] = hi5 ? W0  : Z0p;
        A1.w[3] = hi5 ? W1  : Z1p;
      }
#pragma unroll
      for (int s2 = 0; s2 < 2; ++s2) {
        bf16x8 pa = s2 ? A1.v : A0.v;
        int kk = 32 * kb + 16 * s2 + 8 * hi5;
#pragma unroll
        for (int ht = 0; ht < 2; ++ht) {
          int h = 32 * ht + lo5;
          bf16x8 vf = *reinterpret_cast<const bf16x8*>(
              smem + VT_ + h * 512 + (((2 * kk)) ^ ((h & 7) << 4)));
          if (ht == 0) o0 = __builtin_amdgcn_mfma_f32_32x32x16_bf16(pa, vf, o0, 0, 0, 0);
          else         o1 = __builtin_amdgcn_mfma_f32_32x32x16_bf16(pa, vf, o1, 0, 0, 0);
        }
      }
    }

    lsum += __shfl_xor(lsum, 32);
    float inv = 1.0f / lsum;
    float* ob = out + (size_t)b * T_ * H_;
#pragma unroll
    for (int r = 0; r < 16; ++r) {
      int ridx = (r & 3) + 8 * (r >> 2) + 4 * hi5;
      float invr = __shfl(inv, ridx);
      int row = 32 * wv + ridx;
      ob[row * H_ + lo5]      = o0[r] * invr;
      ob[row * H_ + 32 + lo5] = o1[r] * invr;
    }
  }
}

extern "C" void kernel_launch(void* const* d_in, const int* in_sizes, int n_in,
                              void* d_out, int out_size, void* d_ws, size_t ws_size,
                              hipStream_t stream) {
  const float* x  = (const float*)d_in[0];
  const float* Wq = (const float*)d_in[1];
  const float* bq = (const float*)d_in[2];
  const float* Wk = (const float*)d_in[3];
  const float* bk = (const float*)d_in[4];
  const float* Wv = (const float*)d_in[5];
  const float* bv = (const float*)d_in[6];
  unsigned short* wt = (unsigned short*)d_ws;   // Wt [192][384] bf16 = 147456 B
  float* out = (float*)d_out;

  prep_wt<<<288, 256, 0, stream>>>(Wq, Wk, Wv, wt);
  attn_fused<<<B_, 1024, 106496, stream>>>(x, bq, bk, bv, wt, out);
}

// Round 16
// 64.380 us; speedup vs baseline: 1.4994x; 1.2836x over previous
//
#include <hip/hip_runtime.h>
#include <hip/hip_bf16.h>
#include <stdint.h>

#define B_ 512
#define T_ 256
#define D_ 384
#define H_ 64

typedef __attribute__((ext_vector_type(8))) short bf16x8;
typedef __attribute__((ext_vector_type(4))) float f32x4;
typedef __attribute__((ext_vector_type(16))) float f32x16;

__device__ __forceinline__ unsigned short f2bf(float f) {
  union { float f; unsigned int u; } a; a.f = f;
  unsigned int r = (a.u + 0x7FFFu + ((a.u >> 16) & 1u)) >> 16;
  return (unsigned short)r;
}

__device__ __forceinline__ unsigned int pkbf(float lo, float hi) {
  unsigned int r;
  asm("v_cvt_pk_bf16_f32 %0, %1, %2" : "=v"(r) : "v"(lo), "v"(hi));
  return r;
}

// Build Wt bf16 [192][384]: Wt[n][k] = W_{n/64}[k][n%64]
__global__ void prep_wt(const float* __restrict__ Wq, const float* __restrict__ Wk,
                        const float* __restrict__ Wv, unsigned short* __restrict__ wt) {
  int idx = blockIdx.x * 256 + threadIdx.x;
  if (idx >= 192 * 384) return;
  int n = idx / 384, k = idx - n * 384;
  int sel = n >> 6, c = n & 63;
  const float* W = (sel == 0) ? Wq : ((sel == 1) ? Wk : Wv);
  wt[idx] = f2bf(W[k * 64 + c]);
}

// One block per batch. 1024 threads = 16 waves, LDS 98304 B.
// Phase 1: identical to the 62.9us PASS (16 waves x 16 rows, depth-2 x prefetch,
// Wt halves staged via VGPR). Q@0, K@32768, Vt@65536 (XOR-swizzled).
// Phase 2: PAIR-SPLIT causal triangle. qblock q: owner wave q does kb 0..h-1,
// partner wave q+8 does kb h..q (h = ceil((q+1)/2)); barrier; partner dumps f32
// partials (o + row-lsum) into dead Q/K/V LDS; barrier; owner combines + writes.
// Max serial tiles per wave: 8 -> 4.
__global__ __launch_bounds__(1024) void attn_fused(
    const float* __restrict__ x, const float* __restrict__ bq,
    const float* __restrict__ bk, const float* __restrict__ bv,
    const unsigned short* __restrict__ wt, float* __restrict__ out) {
  extern __shared__ char smem[];
  const int tid = threadIdx.x;
  const int b = blockIdx.x;
  const int wv = tid >> 6, lane = tid & 63;
  const int lo4 = lane & 15, hi4 = lane >> 4;
  const int lo5 = lane & 31, hi5 = lane >> 5;

  const float* xb = x + (size_t)b * T_ * D_;
  const int row0 = 16 * wv + lo4;          // wave owns rows [16wv, 16wv+16)

  f32x4 acc[12];
#pragma unroll
  for (int ct = 0; ct < 12; ++ct) acc[ct] = (f32x4)0.0f;

  float4 xsA[2], xsB[2];                   // depth-2 rolling buffers (32B/lane each)
  {
    const float* p = xb + row0 * D_ + 8 * hi4;     // global k-step 0
    xsA[0] = *reinterpret_cast<const float4*>(p);
    xsA[1] = *reinterpret_cast<const float4*>(p + 4);
  }

  for (int half = 0; half < 2; ++half) {
    // stage Wt half: LDS byte(n, klocal) = n*384 + (2*klocal ^ ((n&7)<<4))
    // unit u = 24*n + (m ^ (n&7)), content = 8 bf16 at Wt[n][192*half + 8m]
#pragma unroll
    for (int i = 0; i < 5; ++i) {
      int u = tid + 1024 * i;           // u < 5120, valid < 4608
      if (u < 4608) {
        int n = u / 24;
        int mp = u - n * 24;
        int m = mp ^ (n & 7);
        const uint4* src = reinterpret_cast<const uint4*>(wt + n * 384 + half * 192 + 8 * m);
        *reinterpret_cast<uint4*>(smem + 16 * u) = *src;
      }
    }
    __syncthreads();
#pragma unroll
    for (int ks6 = 0; ks6 < 6; ++ks6) {
      int g = 6 * half + ks6;
      float4* cur = ((g & 1) == 0) ? xsA : xsB;
      float4* nxt = ((g & 1) == 0) ? xsB : xsA;
      if (g < 11) {
        const float* p = xb + row0 * D_ + 32 * (g + 1) + 8 * hi4;
        nxt[0] = *reinterpret_cast<const float4*>(p);
        nxt[1] = *reinterpret_cast<const float4*>(p + 4);
      }
      union { bf16x8 v; unsigned int w[4]; } A;
      A.w[0] = pkbf(cur[0].x, cur[0].y); A.w[1] = pkbf(cur[0].z, cur[0].w);
      A.w[2] = pkbf(cur[1].x, cur[1].y); A.w[3] = pkbf(cur[1].z, cur[1].w);
      bf16x8 afr = A.v;
#pragma unroll
      for (int ct = 0; ct < 12; ++ct) {
        int n = 16 * ct + lo4;
        int kbyte = (64 * ks6 + 16 * hi4) ^ ((n & 7) << 4);
        bf16x8 bw = *reinterpret_cast<const bf16x8*>(smem + n * 384 + kbyte);
        acc[ct] = __builtin_amdgcn_mfma_f32_16x16x32_bf16(afr, bw, acc[ct], 0, 0, 0);
      }
    }
    __syncthreads();   // done reading this Wt half
  }

  // ---------------- write Q, K, Vt to LDS (bias + bf16) ----------------
  // C-frag (16x16x32): col = lane&15, row(within 16-row tile) = 4*(lane>>4) + reg
#pragma unroll
  for (int ct = 0; ct < 12; ++ct) {
    int n = 16 * ct + lo4;
    float bias = (ct < 4) ? bq[n] : ((ct < 8) ? bk[n - 64] : bv[n - 128]);
    int rowb = 16 * wv + 4 * hi4;
#pragma unroll
    for (int r = 0; r < 4; ++r) {
      int row = rowb + r;
      unsigned short v = f2bf(acc[ct][r] + bias);
      if (ct < 4) {
        int h = n;
        *reinterpret_cast<unsigned short*>(smem + row * 128 + ((2 * h) ^ ((row & 7) << 4))) = v;
      } else if (ct < 8) {
        int h = n - 64;
        *reinterpret_cast<unsigned short*>(smem + 32768 + row * 128 + ((2 * h) ^ ((row & 7) << 4))) = v;
      } else {
        int h = n - 128;
        *reinterpret_cast<unsigned short*>(smem + 65536 + h * 512 + ((2 * row) ^ ((h & 7) << 4))) = v;
      }
    }
  }
  __syncthreads();

  // ---------------- phase 2: pair-split causal triangle (all 16 waves) --------
  const float cexp = 0.09016844005555897f;  // 256^-0.5 * log2(e)
  const int qq = wv & 7;
  const int half_h = (qq + 2) >> 1;               // ceil((qq+1)/2)
  const int kb_begin = (wv < 8) ? 0 : half_h;
  const int kb_end   = (wv < 8) ? half_h : (qq + 1);

  bf16x8 qf[4];
  {
    int row = 32 * qq + lo5;
#pragma unroll
    for (int s = 0; s < 4; ++s)
      qf[s] = *reinterpret_cast<const bf16x8*>(
          smem + row * 128 + (((32 * s + 16 * hi5)) ^ ((row & 7) << 4)));
  }

  f32x16 o0 = (f32x16)0.0f, o1 = (f32x16)0.0f;
  float lsum = 0.0f;

  for (int kb = kb_begin; kb < kb_end; ++kb) {
    // S^T block: St[key][qrow], lane: qrow = lane&31, key = (r&3)+8*(r>>2)+4*hi5
    f32x16 st = (f32x16)0.0f;
    {
      int row = 32 * kb + lo5;
#pragma unroll
      for (int s = 0; s < 4; ++s) {
        bf16x8 kf = *reinterpret_cast<const bf16x8*>(
            smem + 32768 + row * 128 + (((32 * s + 16 * hi5)) ^ ((row & 7) << 4)));
        st = __builtin_amdgcn_mfma_f32_32x32x16_bf16(kf, qf[s], st, 0, 0, 0);
      }
    }
    float p[16];
#pragma unroll
    for (int r = 0; r < 16; ++r) {
      float e = exp2f(cexp * st[r]);
      if (kb == qq) {
        int keyl = (r & 3) + 8 * (r >> 2) + 4 * hi5;
        if (keyl > lo5) e = 0.0f;   // causal mask (diagonal tile)
      }
      p[r] = e;
      lsum += e;
    }

    // pack P (bf16) into PV A-fragments. A-frag needs key = 16*s2 + 8*hi5 + j.
    union { bf16x8 v; unsigned int w[4]; } A0, A1;
    {
      unsigned int X0 = pkbf(p[0], p[1]),  X1 = pkbf(p[2], p[3]);
      unsigned int Y0 = pkbf(p[4], p[5]),  Y1 = pkbf(p[6], p[7]);
      unsigned int X0p = (unsigned int)__shfl_xor((int)X0, 32);
      unsigned int X1p = (unsigned int)__shfl_xor((int)X1, 32);
      unsigned int Y0p = (unsigned int)__shfl_xor((int)Y0, 32);
      unsigned int Y1p = (unsigned int)__shfl_xor((int)Y1, 32);
      A0.w[0] = hi5 ? Y0p : X0;
      A0.w[1] = hi5 ? Y1p : X1;
      A0.w[2] = hi5 ? Y0  : X0p;
      A0.w[3] = hi5 ? Y1  : X1p;
      unsigned int Z0 = pkbf(p[8], p[9]),   Z1 = pkbf(p[10], p[11]);
      unsigned int W0 = pkbf(p[12], p[13]), W1 = pkbf(p[14], p[15]);
      unsigned int Z0p = (unsigned int)__shfl_xor((int)Z0, 32);
      unsigned int Z1p = (unsigned int)__shfl_xor((int)Z1, 32);
      unsigned int W0p = (unsigned int)__shfl_xor((int)W0, 32);
      unsigned int W1p = (unsigned int)__shfl_xor((int)W1, 32);
      A1.w[0] = hi5 ? W0p : Z0;
      A1.w[1] = hi5 ? W1p : Z1;
      A1.w[2] = hi5 ? W0  : Z0p;
      A1.w[3] = hi5 ? W1  : Z1p;
    }
#pragma unroll
    for (int s2 = 0; s2 < 2; ++s2) {
      bf16x8 pa = s2 ? A1.v : A0.v;
      int kk = 32 * kb + 16 * s2 + 8 * hi5;
#pragma unroll
      for (int ht = 0; ht < 2; ++ht) {
        int h = 32 * ht + lo5;
        bf16x8 vf = *reinterpret_cast<const bf16x8*>(
            smem + 65536 + h * 512 + (((2 * kk)) ^ ((h & 7) << 4)));
        if (ht == 0) o0 = __builtin_amdgcn_mfma_f32_32x32x16_bf16(pa, vf, o0, 0, 0, 0);
        else         o1 = __builtin_amdgcn_mfma_f32_32x32x16_bf16(pa, vf, o1, 0, 0, 0);
      }
    }
  }

  lsum += __shfl_xor(lsum, 32);            // merge hi5 halves (per q-row lo5)

  __syncthreads();                         // ALL Q/K/V reads complete block-wide

  if (wv >= 8) {
    // partner: dump f32 partials into dead LDS. o: 8KB per qblock at 8192*qq
    // (row ridx 0..31, stride 256B; o0 cols 0-31, o1 cols 32-63). lsum @65536+.
    char* pbase = smem + 8192 * qq;
#pragma unroll
    for (int r = 0; r < 16; ++r) {
      int ridx = (r & 3) + 8 * (r >> 2) + 4 * hi5;
      *reinterpret_cast<float*>(pbase + ridx * 256 + 4 * lo5)       = o0[r];
      *reinterpret_cast<float*>(pbase + ridx * 256 + 128 + 4 * lo5) = o1[r];
    }
    if (hi5 == 0)
      *reinterpret_cast<float*>(smem + 65536 + 128 * qq + 4 * lo5) = lsum;
  }
  __syncthreads();

  if (wv < 8) {
    // owner: combine partner partials, normalize, write out.
    char* pbase = smem + 8192 * qq;
#pragma unroll
    for (int r = 0; r < 16; ++r) {
      int ridx = (r & 3) + 8 * (r >> 2) + 4 * hi5;
      o0[r] += *reinterpret_cast<const float*>(pbase + ridx * 256 + 4 * lo5);
      o1[r] += *reinterpret_cast<const float*>(pbase + ridx * 256 + 128 + 4 * lo5);
    }
    lsum += *reinterpret_cast<const float*>(smem + 65536 + 128 * qq + 4 * lo5);

    float inv = 1.0f / lsum;
    float* ob = out + (size_t)b * T_ * H_;
#pragma unroll
    for (int r = 0; r < 16; ++r) {
      int ridx = (r & 3) + 8 * (r >> 2) + 4 * hi5;
      float invr = __shfl(inv, ridx);      // lane ridx holds lsum of q-row ridx
      int row = 32 * qq + ridx;
      ob[row * H_ + lo5]      = o0[r] * invr;
      ob[row * H_ + 32 + lo5] = o1[r] * invr;
    }
  }
}

extern "C" void kernel_launch(void* const* d_in, const int* in_sizes, int n_in,
                              void* d_out, int out_size, void* d_ws, size_t ws_size,
                              hipStream_t stream) {
  const float* x  = (const float*)d_in[0];
  const float* Wq = (const float*)d_in[1];
  const float* bq = (const float*)d_in[2];
  const float* Wk = (const float*)d_in[3];
  const float* bk = (const float*)d_in[4];
  const float* Wv = (const float*)d_in[5];
  const float* bv = (const float*)d_in[6];
  unsigned short* wt = (unsigned short*)d_ws;   // 192*384 bf16 = 147456 B
  float* out = (float*)d_out;

  prep_wt<<<288, 256, 0, stream>>>(Wq, Wk, Wv, wt);
  attn_fused<<<B_, 1024, 98304, stream>>>(x, bq, bk, bv, wt, out);
}